// Round 7
// baseline (706.850 us; speedup 1.0000x reference)
//
#include <hip/hip_runtime.h>
#include <math.h>

#define Bq 16
#define Tq 34
#define Nq 1000
#define Cq 32      // CIN == DC == 32
#define OCq 64
#define Eq 16000
#define TPq 32     // T - dilation
#define Gq (Bq*TPq)  // 512 graphs

typedef _Float16 f16;
typedef f16  f16x8 __attribute__((ext_vector_type(8)));
typedef float f32x4 __attribute__((ext_vector_type(4)));

__device__ __forceinline__ float fast_tanh(float x) {
    float xc = fminf(fmaxf(x, -15.f), 15.f);
    float u  = __expf(2.f * xc);
    return 1.f - 2.f * __builtin_amdgcn_rcpf(u + 1.f);
}
__device__ __forceinline__ float fast_sigmoid(float x) {
    float xc = fminf(fmaxf(x, -30.f), 30.f);
    return __builtin_amdgcn_rcpf(1.f + __expf(-xc));
}
__device__ __forceinline__ unsigned bf16_bits(float f) {
    unsigned u = __float_as_uint(f);
    return (u + 0x7fffu + ((u >> 16) & 1u)) >> 16;   // RNE
}
__device__ __forceinline__ unsigned pack_bf16x2(float lo, float hi) {
    return bf16_bits(lo) | (bf16_bits(hi) << 16);
}

// ---------------------------------------------------------------------------
// K0: precompute f16 MFMA A-fragments (conv weights, wgcn) + transposed
// wout (woTg[c*64+o] = wout[o*32+c]) for k_gcn's scalar-load epilogue.
// ---------------------------------------------------------------------------
__global__ __launch_bounds__(1024) void k_prep(
    const float* __restrict__ wg1, const float* __restrict__ wg2,
    const float* __restrict__ wgcn, const float* __restrict__ wout,
    f16* __restrict__ fragbuf, float* __restrict__ woTg)
{
    const int tid = threadIdx.x;
    if (tid < 512) {
        const int fid  = tid >> 6;            // 0..7
        const int lane = tid & 63;
        const int gate  = fid >> 2;
        const int otile = (fid >> 1) & 1;
        const int ks    = fid & 1;            // = tap
        const float* w = gate ? wg2 : wg1;    // layout [o][c][1][2]
        const int o = otile*16 + (lane & 15);
        f16* dst = fragbuf + (size_t)fid*512 + lane*8;
        #pragma unroll
        for (int j = 0; j < 8; j++) {
            const int c = (lane >> 4)*8 + j;
            dst[j] = (f16)w[o*64 + c*2 + ks];
        }
    } else if (tid < 640) {
        const int l2 = tid - 512;
        const int ctile = l2 >> 6;
        const int lane  = l2 & 63;
        const int c = ctile*16 + (lane & 15);
        f16* dst = fragbuf + (size_t)8*512 + ((size_t)ctile*64 + lane)*8;
        #pragma unroll
        for (int j = 0; j < 8; j++) {
            const int o = (lane >> 4)*8 + j;
            dst[j] = (f16)wgcn[c*32 + o];     // wgcn[c][d=o]
        }
    }
    for (int k = tid; k < Cq*OCq; k += 1024)
        woTg[k] = wout[(k & 63)*Cq + (k >> 6)];
}

// ---------------------------------------------------------------------------
// K1: MFMA gated conv + GCN linear. xwt element (uint2) index:
//   (((n*2+s)*4 + c8)*256 + gl)*2 + half,  c8=c>>3, half=(c>>2)&1
// -> consumers read uint4; one wave's store covers dense 256B rows.
// ---------------------------------------------------------------------------
__global__ __launch_bounds__(128) void k_conv(
    const float* __restrict__ x,
    const float* __restrict__ bg1, const float* __restrict__ bg2,
    const f16* __restrict__ fragbuf,
    float* __restrict__ out1, uint2* __restrict__ xw2)
{
    __shared__ f16 goS[32*40];            // [t][o], stride 40 h (80B rows)
    const int tid  = threadIdx.x;
    const int w    = tid >> 6;            // wave = o-tile
    const int lane = tid & 63;
    const int b    = blockIdx.x / Nq;
    const int n    = blockIdx.x % Nq;
    const int tq   = lane & 15;
    const int cg   = lane >> 4;

    const uint4* fb = (const uint4*)fragbuf;      // 16B per lane-entry
    union cvu { uint4 u; f16x8 h; };
    cvu A1k0; A1k0.u = fb[(0 + w*2 + 0)*64 + lane];
    cvu A1k1; A1k1.u = fb[(0 + w*2 + 1)*64 + lane];
    cvu A2k0; A2k0.u = fb[(4 + w*2 + 0)*64 + lane];
    cvu A2k1; A2k1.u = fb[(4 + w*2 + 1)*64 + lane];

    // B-frags: lane -> B[k=(cg*8+j) + ks*32][t=tt*16+tq] = x[b][t+2ks][n][c]
    f16x8 Bf[2][2];
    #pragma unroll
    for (int tt = 0; tt < 2; tt++) {
        #pragma unroll
        for (int ks = 0; ks < 2; ks++) {
            const float* xp = x + (((size_t)(b*Tq + tt*16 + tq + ks*2))*Nq + n)*Cq + cg*8;
            const float4 lo = *(const float4*)xp;
            const float4 hi = *(const float4*)(xp + 4);
            f16x8 h;
            h[0]=(f16)lo.x; h[1]=(f16)lo.y; h[2]=(f16)lo.z; h[3]=(f16)lo.w;
            h[4]=(f16)hi.x; h[5]=(f16)hi.y; h[6]=(f16)hi.z; h[7]=(f16)hi.w;
            Bf[tt][ks] = h;
        }
    }

    f32x4 acc1[2] = {{0.f,0.f,0.f,0.f},{0.f,0.f,0.f,0.f}};
    f32x4 acc2[2] = {{0.f,0.f,0.f,0.f},{0.f,0.f,0.f,0.f}};
    #pragma unroll
    for (int tt = 0; tt < 2; tt++) {
        acc1[tt] = __builtin_amdgcn_mfma_f32_16x16x32_f16(A1k0.h, Bf[tt][0], acc1[tt], 0,0,0);
        acc1[tt] = __builtin_amdgcn_mfma_f32_16x16x32_f16(A1k1.h, Bf[tt][1], acc1[tt], 0,0,0);
        acc2[tt] = __builtin_amdgcn_mfma_f32_16x16x32_f16(A2k0.h, Bf[tt][0], acc2[tt], 0,0,0);
        acc2[tt] = __builtin_amdgcn_mfma_f32_16x16x32_f16(A2k1.h, Bf[tt][1], acc2[tt], 0,0,0);
    }

    const int obase = w*16 + cg*4;
    const float4 b1 = *(const float4*)&bg1[obase];
    const float4 b2 = *(const float4*)&bg2[obase];
    const float b1a[4] = {b1.x,b1.y,b1.z,b1.w};
    const float b2a[4] = {b2.x,b2.y,b2.z,b2.w};

    float* o1base = out1 + ((size_t)b*Cq + obase)*(Nq*TPq) + (size_t)n*TPq;
    #pragma unroll
    for (int tt = 0; tt < 2; tt++) {
        const int t = tt*16 + tq;
        f16* gp = &goS[t*40 + obase];
        #pragma unroll
        for (int r = 0; r < 4; r++) {
            const float a1 = acc1[tt][r] + b1a[r];
            const float a2 = acc2[tt][r] + b2a[r];
            const float go = fast_tanh(a1) * fast_sigmoid(a2);
            __builtin_nontemporal_store(go, &o1base[(size_t)r*(Nq*TPq) + t]);
            gp[r] = (f16)go;
        }
    }
    __syncthreads();

    // Stage 2: xw[c][t], K=32 over o. B2 lane: go[o=cg*8+j][t], 16B-aligned.
    cvu A2f; A2f.u = fb[8*64 + w*64 + lane];       // c-tile = w
    #pragma unroll
    for (int tt = 0; tt < 2; tt++) {
        const int t = tt*16 + tq;
        const f16x8 B2 = *(const f16x8*)&goS[t*40 + cg*8];
        f32x4 xa = {0.f,0.f,0.f,0.f};
        xa = __builtin_amdgcn_mfma_f32_16x16x32_f16(A2f.h, B2, xa, 0,0,0);
        const int g  = b*32 + t;
        const int s  = g >> 8;
        const int gl = g & 255;
        const int cbase = w*16 + cg*4;             // row = c
        uint2 u;
        u.x = pack_bf16x2(xa[0], xa[1]);
        u.y = pack_bf16x2(xa[2], xa[3]);
        const int c8   = cbase >> 3;
        const int half = (cbase >> 2) & 1;
        xw2[(((size_t)(n*2 + s)*4 + c8)*256 + gl)*2 + half] = u;
    }
}

// ---------------------------------------------------------------------------
// Single-block graph prep: LDS degree/count atomics -> LDS scan -> CSR fill.
// ---------------------------------------------------------------------------
__global__ __launch_bounds__(1024) void k_graph(
    const int* __restrict__ ei, const float* __restrict__ ew,
    float* __restrict__ dis_g, int* __restrict__ rowstart_g,
    int* __restrict__ col, float* __restrict__ val)
{
    __shared__ float deg[Nq];
    __shared__ int   cnt[Nq];
    __shared__ int   pos[Nq];
    __shared__ float diss[Nq];
    __shared__ int   ssum[1024];
    const int tid = threadIdx.x;

    for (int n = tid; n < Nq; n += 1024) { deg[n] = 1.0f; cnt[n] = 0; }
    __syncthreads();
    for (int e = tid; e < Eq; e += 1024) {
        int d = ei[Eq + e];
        atomicAdd(&deg[d], ew[e]);
        atomicAdd(&cnt[d], 1);
    }
    __syncthreads();
    const int v = (tid < Nq) ? cnt[tid] : 0;
    ssum[tid] = v;
    __syncthreads();
    for (int off = 1; off < 1024; off <<= 1) {
        int add = (tid >= off) ? ssum[tid - off] : 0;
        __syncthreads();
        ssum[tid] += add;
        __syncthreads();
    }
    if (tid < Nq) {
        int excl = ssum[tid] - v;
        pos[tid] = excl;
        rowstart_g[tid] = excl;
        float di = rsqrtf(deg[tid]);    // deg >= 1 (self loop)
        diss[tid] = di;
        dis_g[tid] = di;
        if (tid == Nq-1) rowstart_g[Nq] = ssum[tid];
    }
    __syncthreads();
    for (int e = tid; e < Eq; e += 1024) {
        int srce = ei[e], d = ei[Eq + e];
        int slot = atomicAdd(&pos[d], 1);
        col[slot] = srce;
        val[slot] = diss[srce] * ew[e] * diss[d];
    }
}

// ---------------------------------------------------------------------------
// K3: SpMM gather + fused 1x1 conv.
// Grid = 1000 rows x 8 (chunk,slice) pairs; pair = blockIdx & 7 so each XCD
// (round-robin dispatch) owns ONE 64-graph x 1-slice chunk = 4 MB of xwt ->
// L2-resident gathers. Block = 1 wave; edge loop software-pipelined.
// ---------------------------------------------------------------------------
#define ACC8(vv, c8) do { \
    acc[8*(c8)+0] = fmaf(sv, __uint_as_float((vv).x << 16),          acc[8*(c8)+0]); \
    acc[8*(c8)+1] = fmaf(sv, __uint_as_float((vv).x & 0xffff0000u), acc[8*(c8)+1]); \
    acc[8*(c8)+2] = fmaf(sv, __uint_as_float((vv).y << 16),          acc[8*(c8)+2]); \
    acc[8*(c8)+3] = fmaf(sv, __uint_as_float((vv).y & 0xffff0000u), acc[8*(c8)+3]); \
    acc[8*(c8)+4] = fmaf(sv, __uint_as_float((vv).z << 16),          acc[8*(c8)+4]); \
    acc[8*(c8)+5] = fmaf(sv, __uint_as_float((vv).z & 0xffff0000u), acc[8*(c8)+5]); \
    acc[8*(c8)+6] = fmaf(sv, __uint_as_float((vv).w << 16),          acc[8*(c8)+6]); \
    acc[8*(c8)+7] = fmaf(sv, __uint_as_float((vv).w & 0xffff0000u), acc[8*(c8)+7]); \
} while (0)

__global__ __launch_bounds__(64) void k_gcn(
    const uint4* __restrict__ xw4, const int* __restrict__ rowstart,
    const int* __restrict__ colv, const float* __restrict__ valv,
    const float* __restrict__ dis, const float* __restrict__ bgcn,
    const float* __restrict__ woTg, const float* __restrict__ bout,
    float* __restrict__ y)
{
    __shared__ int   scol[64];
    __shared__ float sval[64];
    const int tid  = threadIdx.x;
    const int pair = blockIdx.x & 7;       // chunk*2 + s  -> one per XCD
    const int i    = blockIdx.x >> 3;
    const int s    = pair & 1;
    const int gl   = (pair >> 1)*64 + tid; // graph-in-slice 0..255

    float acc[Cq];
    #pragma unroll
    for (int c = 0; c < Cq; c++) acc[c] = 0.f;

    const int r0 = rowstart[i], r1 = rowstart[i+1];
    const int total = r1 - r0 + 1;         // + self loop
    const float dii = dis[i];
    const uint4* xg = xw4 + (size_t)s*1024 + gl;

    for (int base = 0; base < total; base += 64) {
        const int cnt = min(64, total - base);
        __syncthreads();
        if (tid < cnt) {
            int k = base + tid;
            if (k == 0) { scol[tid] = i; sval[tid] = dii*dii; }
            else        { scol[tid] = colv[r0 + k - 1]; sval[tid] = valv[r0 + k - 1]; }
        }
        __syncthreads();

        // software-pipelined gather: prefetch edge k+1 during edge k's FMAs
        const uint4* rp = xg + (size_t)scol[0]*2048;
        float sv = sval[0];
        uint4 va0 = rp[0], va1 = rp[256], va2 = rp[512], va3 = rp[768];
        for (int k = 1; k < cnt; k++) {
            const uint4* rq = xg + (size_t)scol[k]*2048;
            const float svn = sval[k];
            const uint4 vb0 = rq[0], vb1 = rq[256], vb2 = rq[512], vb3 = rq[768];
            ACC8(va0, 0); ACC8(va1, 1); ACC8(va2, 2); ACC8(va3, 3);
            va0 = vb0; va1 = vb1; va2 = vb2; va3 = vb3; sv = svn;
        }
        ACC8(va0, 0); ACC8(va1, 1); ACC8(va2, 2); ACC8(va3, 3);
    }

    #pragma unroll
    for (int c4 = 0; c4 < 8; c4++) {
        const float4 bg = *(const float4*)&bgcn[4*c4];   // uniform
        acc[4*c4+0] += bg.x; acc[4*c4+1] += bg.y;
        acc[4*c4+2] += bg.z; acc[4*c4+3] += bg.w;
    }

    const int g = s*256 + gl;
    float* yp = y + ((size_t)g*Nq + i)*OCq;
    #pragma unroll
    for (int h = 0; h < 2; h++) {
        float yr[32];
        #pragma unroll
        for (int q = 0; q < 32; q++) yr[q] = bout[h*32 + q];   // uniform
        #pragma unroll
        for (int c = 0; c < Cq; c++) {
            const float ga = acc[c];
            const float* wrow = &woTg[c*OCq + h*32];
            #pragma unroll
            for (int q4 = 0; q4 < 8; q4++) {
                const float4 w = *(const float4*)&wrow[4*q4];  // uniform scalar
                yr[4*q4+0] = fmaf(ga, w.x, yr[4*q4+0]);
                yr[4*q4+1] = fmaf(ga, w.y, yr[4*q4+1]);
                yr[4*q4+2] = fmaf(ga, w.z, yr[4*q4+2]);
                yr[4*q4+3] = fmaf(ga, w.w, yr[4*q4+3]);
            }
        }
        #pragma unroll
        for (int q4 = 0; q4 < 8; q4++) {
            f32x4 vv;
            vv[0] = yr[4*q4+0]; vv[1] = yr[4*q4+1];
            vv[2] = yr[4*q4+2]; vv[3] = yr[4*q4+3];
            __builtin_nontemporal_store(vv, (f32x4*)&yp[h*32 + 4*q4]);
        }
    }
}

// ---------------------------------------------------------------------------
extern "C" void kernel_launch(void* const* d_in, const int* in_sizes, int n_in,
                              void* d_out, int out_size, void* d_ws, size_t ws_size,
                              hipStream_t stream)
{
    const float* x    = (const float*)d_in[0];
    const int*   ei   = (const int*)  d_in[1];
    const float* ew   = (const float*)d_in[2];
    const float* wg1  = (const float*)d_in[3];
    const float* bg1  = (const float*)d_in[4];
    const float* wg2  = (const float*)d_in[5];
    const float* bg2  = (const float*)d_in[6];
    const float* wgcn = (const float*)d_in[7];
    const float* bgcn = (const float*)d_in[8];
    const float* wout = (const float*)d_in[9];
    const float* bout = (const float*)d_in[10];

    float* out1 = (float*)d_out;                         // [B,32,N,32]
    float* y    = out1 + (size_t)Bq*Cq*Nq*TPq;           // [B,32,N,64]

    char* ws = (char*)d_ws;
    uint2* xwt = (uint2*)ws; ws += sizeof(unsigned short)*(size_t)Nq*Gq*Cq; // 32.8MB
    float* dis = (float*)ws; ws += sizeof(float)*Nq;
    float* val = (float*)ws; ws += sizeof(float)*Eq;
    int*   col = (int*)ws;   ws += sizeof(int)*Eq;
    int*   rowstart = (int*)ws; ws += sizeof(int)*(Nq+4);
    f16*   fragbuf  = (f16*)ws; ws += sizeof(f16)*(10*512);
    float* woTg     = (float*)ws; ws += sizeof(float)*Cq*OCq;

    k_prep<<<1, 1024, 0, stream>>>(wg1, wg2, wgcn, wout, fragbuf, woTg);
    k_conv<<<Bq*Nq, 128, 0, stream>>>(x, bg1, bg2, fragbuf, out1, xwt);
    k_graph<<<1, 1024, 0, stream>>>(ei, ew, dis, rowstart, col, val);
    k_gcn<<<8*Nq, 64, 0, stream>>>((const uint4*)xwt, rowstart, col, val, dis,
                                   bgcn, woTg, bout, y);
}

// Round 8
// 453.740 us; speedup vs baseline: 1.5578x; 1.5578x over previous
//
#include <hip/hip_runtime.h>
#include <math.h>

#define Bq 16
#define Tq 34
#define Nq 1000
#define Cq 32      // CIN == DC == 32
#define OCq 64
#define Eq 16000
#define TPq 32     // T - dilation
#define Gq (Bq*TPq)  // 512 graphs

typedef _Float16 f16;
typedef f16  f16x8 __attribute__((ext_vector_type(8)));
typedef float f32x4 __attribute__((ext_vector_type(4)));

__device__ __forceinline__ float fast_tanh(float x) {
    float xc = fminf(fmaxf(x, -15.f), 15.f);
    float u  = __expf(2.f * xc);
    return 1.f - 2.f * __builtin_amdgcn_rcpf(u + 1.f);
}
__device__ __forceinline__ float fast_sigmoid(float x) {
    float xc = fminf(fmaxf(x, -30.f), 30.f);
    return __builtin_amdgcn_rcpf(1.f + __expf(-xc));
}
__device__ __forceinline__ unsigned bf16_bits(float f) {
    unsigned u = __float_as_uint(f);
    return (u + 0x7fffu + ((u >> 16) & 1u)) >> 16;   // RNE
}
__device__ __forceinline__ unsigned pack_bf16x2(float lo, float hi) {
    return bf16_bits(lo) | (bf16_bits(hi) << 16);
}

// ---------------------------------------------------------------------------
// K0: precompute f16 MFMA A-fragments (conv weights, wgcn) + transposed
// wout (woTg[c*64+o] = wout[o*32+c]) for k_gcn's scalar-load epilogue.
// ---------------------------------------------------------------------------
__global__ __launch_bounds__(1024) void k_prep(
    const float* __restrict__ wg1, const float* __restrict__ wg2,
    const float* __restrict__ wgcn, const float* __restrict__ wout,
    f16* __restrict__ fragbuf, float* __restrict__ woTg)
{
    const int tid = threadIdx.x;
    if (tid < 512) {
        const int fid  = tid >> 6;            // 0..7
        const int lane = tid & 63;
        const int gate  = fid >> 2;
        const int otile = (fid >> 1) & 1;
        const int ks    = fid & 1;            // = tap
        const float* w = gate ? wg2 : wg1;    // layout [o][c][1][2]
        const int o = otile*16 + (lane & 15);
        f16* dst = fragbuf + (size_t)fid*512 + lane*8;
        #pragma unroll
        for (int j = 0; j < 8; j++) {
            const int c = (lane >> 4)*8 + j;
            dst[j] = (f16)w[o*64 + c*2 + ks];
        }
    } else if (tid < 640) {
        const int l2 = tid - 512;
        const int ctile = l2 >> 6;
        const int lane  = l2 & 63;
        const int c = ctile*16 + (lane & 15);
        f16* dst = fragbuf + (size_t)8*512 + ((size_t)ctile*64 + lane)*8;
        #pragma unroll
        for (int j = 0; j < 8; j++) {
            const int o = (lane >> 4)*8 + j;
            dst[j] = (f16)wgcn[c*32 + o];     // wgcn[c][d=o]
        }
    }
    for (int k = tid; k < Cq*OCq; k += 1024)
        woTg[k] = wout[(k & 63)*Cq + (k >> 6)];
}

// ---------------------------------------------------------------------------
// K1: MFMA gated conv + GCN linear. xwt element (uint2) index:
//   (((n*2+s)*4 + c8)*256 + gl)*2 + half,  c8=c>>3, half=(c>>2)&1
// -> consumers read uint4; one wave's store covers dense 256B rows.
// Plain stores only: out1's per-lane stores are scattered 4B/16B chunks,
// which REQUIRE L2 write-merging (nontemporal tripled HBM write traffic
// in R7 -- WRITE_SIZE 135->421 MB).
// ---------------------------------------------------------------------------
__global__ __launch_bounds__(128) void k_conv(
    const float* __restrict__ x,
    const float* __restrict__ bg1, const float* __restrict__ bg2,
    const f16* __restrict__ fragbuf,
    float* __restrict__ out1, uint2* __restrict__ xw2)
{
    __shared__ f16 goS[32*40];            // [t][o], stride 40 h (80B rows)
    const int tid  = threadIdx.x;
    const int w    = tid >> 6;            // wave = o-tile
    const int lane = tid & 63;
    const int b    = blockIdx.x / Nq;
    const int n    = blockIdx.x % Nq;
    const int tq   = lane & 15;
    const int cg   = lane >> 4;

    const uint4* fb = (const uint4*)fragbuf;      // 16B per lane-entry
    union cvu { uint4 u; f16x8 h; };
    cvu A1k0; A1k0.u = fb[(0 + w*2 + 0)*64 + lane];
    cvu A1k1; A1k1.u = fb[(0 + w*2 + 1)*64 + lane];
    cvu A2k0; A2k0.u = fb[(4 + w*2 + 0)*64 + lane];
    cvu A2k1; A2k1.u = fb[(4 + w*2 + 1)*64 + lane];

    // B-frags: lane -> B[k=(cg*8+j) + ks*32][t=tt*16+tq] = x[b][t+2ks][n][c]
    f16x8 Bf[2][2];
    #pragma unroll
    for (int tt = 0; tt < 2; tt++) {
        #pragma unroll
        for (int ks = 0; ks < 2; ks++) {
            const float* xp = x + (((size_t)(b*Tq + tt*16 + tq + ks*2))*Nq + n)*Cq + cg*8;
            const float4 lo = *(const float4*)xp;
            const float4 hi = *(const float4*)(xp + 4);
            f16x8 h;
            h[0]=(f16)lo.x; h[1]=(f16)lo.y; h[2]=(f16)lo.z; h[3]=(f16)lo.w;
            h[4]=(f16)hi.x; h[5]=(f16)hi.y; h[6]=(f16)hi.z; h[7]=(f16)hi.w;
            Bf[tt][ks] = h;
        }
    }

    f32x4 acc1[2] = {{0.f,0.f,0.f,0.f},{0.f,0.f,0.f,0.f}};
    f32x4 acc2[2] = {{0.f,0.f,0.f,0.f},{0.f,0.f,0.f,0.f}};
    #pragma unroll
    for (int tt = 0; tt < 2; tt++) {
        acc1[tt] = __builtin_amdgcn_mfma_f32_16x16x32_f16(A1k0.h, Bf[tt][0], acc1[tt], 0,0,0);
        acc1[tt] = __builtin_amdgcn_mfma_f32_16x16x32_f16(A1k1.h, Bf[tt][1], acc1[tt], 0,0,0);
        acc2[tt] = __builtin_amdgcn_mfma_f32_16x16x32_f16(A2k0.h, Bf[tt][0], acc2[tt], 0,0,0);
        acc2[tt] = __builtin_amdgcn_mfma_f32_16x16x32_f16(A2k1.h, Bf[tt][1], acc2[tt], 0,0,0);
    }

    const int obase = w*16 + cg*4;
    const float4 b1 = *(const float4*)&bg1[obase];
    const float4 b2 = *(const float4*)&bg2[obase];
    const float b1a[4] = {b1.x,b1.y,b1.z,b1.w};
    const float b2a[4] = {b2.x,b2.y,b2.z,b2.w};

    float* o1base = out1 + ((size_t)b*Cq + obase)*(Nq*TPq) + (size_t)n*TPq;
    #pragma unroll
    for (int tt = 0; tt < 2; tt++) {
        const int t = tt*16 + tq;
        f16* gp = &goS[t*40 + obase];
        #pragma unroll
        for (int r = 0; r < 4; r++) {
            const float a1 = acc1[tt][r] + b1a[r];
            const float a2 = acc2[tt][r] + b2a[r];
            const float go = fast_tanh(a1) * fast_sigmoid(a2);
            o1base[(size_t)r*(Nq*TPq) + t] = go;
            gp[r] = (f16)go;
        }
    }
    __syncthreads();

    // Stage 2: xw[c][t], K=32 over o. B2 lane: go[o=cg*8+j][t], 16B-aligned.
    cvu A2f; A2f.u = fb[8*64 + w*64 + lane];       // c-tile = w
    #pragma unroll
    for (int tt = 0; tt < 2; tt++) {
        const int t = tt*16 + tq;
        const f16x8 B2 = *(const f16x8*)&goS[t*40 + cg*8];
        f32x4 xa = {0.f,0.f,0.f,0.f};
        xa = __builtin_amdgcn_mfma_f32_16x16x32_f16(A2f.h, B2, xa, 0,0,0);
        const int g  = b*32 + t;
        const int s  = g >> 8;
        const int gl = g & 255;
        const int cbase = w*16 + cg*4;             // row = c
        uint2 u;
        u.x = pack_bf16x2(xa[0], xa[1]);
        u.y = pack_bf16x2(xa[2], xa[3]);
        const int c8   = cbase >> 3;
        const int half = (cbase >> 2) & 1;
        xw2[(((size_t)(n*2 + s)*4 + c8)*256 + gl)*2 + half] = u;
    }
}

// ---------------------------------------------------------------------------
// Single-block graph prep: LDS degree/count atomics -> LDS scan -> CSR fill.
// ---------------------------------------------------------------------------
__global__ __launch_bounds__(1024) void k_graph(
    const int* __restrict__ ei, const float* __restrict__ ew,
    float* __restrict__ dis_g, int* __restrict__ rowstart_g,
    int* __restrict__ col, float* __restrict__ val)
{
    __shared__ float deg[Nq];
    __shared__ int   cnt[Nq];
    __shared__ int   pos[Nq];
    __shared__ float diss[Nq];
    __shared__ int   ssum[1024];
    const int tid = threadIdx.x;

    for (int n = tid; n < Nq; n += 1024) { deg[n] = 1.0f; cnt[n] = 0; }
    __syncthreads();
    for (int e = tid; e < Eq; e += 1024) {
        int d = ei[Eq + e];
        atomicAdd(&deg[d], ew[e]);
        atomicAdd(&cnt[d], 1);
    }
    __syncthreads();
    const int v = (tid < Nq) ? cnt[tid] : 0;
    ssum[tid] = v;
    __syncthreads();
    for (int off = 1; off < 1024; off <<= 1) {
        int add = (tid >= off) ? ssum[tid - off] : 0;
        __syncthreads();
        ssum[tid] += add;
        __syncthreads();
    }
    if (tid < Nq) {
        int excl = ssum[tid] - v;
        pos[tid] = excl;
        rowstart_g[tid] = excl;
        float di = rsqrtf(deg[tid]);    // deg >= 1 (self loop)
        diss[tid] = di;
        dis_g[tid] = di;
        if (tid == Nq-1) rowstart_g[Nq] = ssum[tid];
    }
    __syncthreads();
    for (int e = tid; e < Eq; e += 1024) {
        int srce = ei[e], d = ei[Eq + e];
        int slot = atomicAdd(&pos[d], 1);
        col[slot] = srce;
        val[slot] = diss[srce] * ew[e] * diss[d];
    }
}

// ---------------------------------------------------------------------------
// K3: SpMM gather + fused 1x1 conv.
// Grid = 1000 rows x 8 (chunk,slice) pairs; pair = blockIdx & 7 so each XCD
// (round-robin dispatch) owns ONE 64-graph x 1-slice chunk = 4 MB of xwt ->
// L2-resident gathers (R7: FETCH 221->142 MB). Block = 1 wave; edge loop
// software-pipelined. PLAIN stores for y: scattered per-lane 16B chunks need
// L2 write-merging (nontemporal was a 3.1x write amplification in R7).
// ---------------------------------------------------------------------------
#define ACC8(vv, c8) do { \
    acc[8*(c8)+0] = fmaf(sv, __uint_as_float((vv).x << 16),          acc[8*(c8)+0]); \
    acc[8*(c8)+1] = fmaf(sv, __uint_as_float((vv).x & 0xffff0000u), acc[8*(c8)+1]); \
    acc[8*(c8)+2] = fmaf(sv, __uint_as_float((vv).y << 16),          acc[8*(c8)+2]); \
    acc[8*(c8)+3] = fmaf(sv, __uint_as_float((vv).y & 0xffff0000u), acc[8*(c8)+3]); \
    acc[8*(c8)+4] = fmaf(sv, __uint_as_float((vv).z << 16),          acc[8*(c8)+4]); \
    acc[8*(c8)+5] = fmaf(sv, __uint_as_float((vv).z & 0xffff0000u), acc[8*(c8)+5]); \
    acc[8*(c8)+6] = fmaf(sv, __uint_as_float((vv).w << 16),          acc[8*(c8)+6]); \
    acc[8*(c8)+7] = fmaf(sv, __uint_as_float((vv).w & 0xffff0000u), acc[8*(c8)+7]); \
} while (0)

__global__ __launch_bounds__(64) void k_gcn(
    const uint4* __restrict__ xw4, const int* __restrict__ rowstart,
    const int* __restrict__ colv, const float* __restrict__ valv,
    const float* __restrict__ dis, const float* __restrict__ bgcn,
    const float* __restrict__ woTg, const float* __restrict__ bout,
    float* __restrict__ y)
{
    __shared__ int   scol[64];
    __shared__ float sval[64];
    const int tid  = threadIdx.x;
    const int pair = blockIdx.x & 7;       // chunk*2 + s  -> one per XCD
    const int i    = blockIdx.x >> 3;
    const int s    = pair & 1;
    const int gl   = (pair >> 1)*64 + tid; // graph-in-slice 0..255

    float acc[Cq];
    #pragma unroll
    for (int c = 0; c < Cq; c++) acc[c] = 0.f;

    const int r0 = rowstart[i], r1 = rowstart[i+1];
    const int total = r1 - r0 + 1;         // + self loop
    const float dii = dis[i];
    const uint4* xg = xw4 + (size_t)s*1024 + gl;

    for (int base = 0; base < total; base += 64) {
        const int cnt = min(64, total - base);
        __syncthreads();
        if (tid < cnt) {
            int k = base + tid;
            if (k == 0) { scol[tid] = i; sval[tid] = dii*dii; }
            else        { scol[tid] = colv[r0 + k - 1]; sval[tid] = valv[r0 + k - 1]; }
        }
        __syncthreads();

        // software-pipelined gather: prefetch edge k+1 during edge k's FMAs
        const uint4* rp = xg + (size_t)scol[0]*2048;
        float sv = sval[0];
        uint4 va0 = rp[0], va1 = rp[256], va2 = rp[512], va3 = rp[768];
        for (int k = 1; k < cnt; k++) {
            const uint4* rq = xg + (size_t)scol[k]*2048;
            const float svn = sval[k];
            const uint4 vb0 = rq[0], vb1 = rq[256], vb2 = rq[512], vb3 = rq[768];
            ACC8(va0, 0); ACC8(va1, 1); ACC8(va2, 2); ACC8(va3, 3);
            va0 = vb0; va1 = vb1; va2 = vb2; va3 = vb3; sv = svn;
        }
        ACC8(va0, 0); ACC8(va1, 1); ACC8(va2, 2); ACC8(va3, 3);
    }

    #pragma unroll
    for (int c4 = 0; c4 < 8; c4++) {
        const float4 bg = *(const float4*)&bgcn[4*c4];   // uniform
        acc[4*c4+0] += bg.x; acc[4*c4+1] += bg.y;
        acc[4*c4+2] += bg.z; acc[4*c4+3] += bg.w;
    }

    const int g = s*256 + gl;
    float* yp = y + ((size_t)g*Nq + i)*OCq;
    #pragma unroll
    for (int h = 0; h < 2; h++) {
        float yr[32];
        #pragma unroll
        for (int q = 0; q < 32; q++) yr[q] = bout[h*32 + q];   // uniform
        #pragma unroll
        for (int c = 0; c < Cq; c++) {
            const float ga = acc[c];
            const float* wrow = &woTg[c*OCq + h*32];
            #pragma unroll
            for (int q4 = 0; q4 < 8; q4++) {
                const float4 w = *(const float4*)&wrow[4*q4];  // uniform scalar
                yr[4*q4+0] = fmaf(ga, w.x, yr[4*q4+0]);
                yr[4*q4+1] = fmaf(ga, w.y, yr[4*q4+1]);
                yr[4*q4+2] = fmaf(ga, w.z, yr[4*q4+2]);
                yr[4*q4+3] = fmaf(ga, w.w, yr[4*q4+3]);
            }
        }
        #pragma unroll
        for (int q4 = 0; q4 < 8; q4++) {
            float4 vv;
            vv.x = yr[4*q4+0]; vv.y = yr[4*q4+1];
            vv.z = yr[4*q4+2]; vv.w = yr[4*q4+3];
            *(float4*)&yp[h*32 + 4*q4] = vv;
        }
    }
}

// ---------------------------------------------------------------------------
extern "C" void kernel_launch(void* const* d_in, const int* in_sizes, int n_in,
                              void* d_out, int out_size, void* d_ws, size_t ws_size,
                              hipStream_t stream)
{
    const float* x    = (const float*)d_in[0];
    const int*   ei   = (const int*)  d_in[1];
    const float* ew   = (const float*)d_in[2];
    const float* wg1  = (const float*)d_in[3];
    const float* bg1  = (const float*)d_in[4];
    const float* wg2  = (const float*)d_in[5];
    const float* bg2  = (const float*)d_in[6];
    const float* wgcn = (const float*)d_in[7];
    const float* bgcn = (const float*)d_in[8];
    const float* wout = (const float*)d_in[9];
    const float* bout = (const float*)d_in[10];

    float* out1 = (float*)d_out;                         // [B,32,N,32]
    float* y    = out1 + (size_t)Bq*Cq*Nq*TPq;           // [B,32,N,64]

    char* ws = (char*)d_ws;
    uint2* xwt = (uint2*)ws; ws += sizeof(unsigned short)*(size_t)Nq*Gq*Cq; // 32.8MB
    float* dis = (float*)ws; ws += sizeof(float)*Nq;
    float* val = (float*)ws; ws += sizeof(float)*Eq;
    int*   col = (int*)ws;   ws += sizeof(int)*Eq;
    int*   rowstart = (int*)ws; ws += sizeof(int)*(Nq+4);
    f16*   fragbuf  = (f16*)ws; ws += sizeof(f16)*(10*512);
    float* woTg     = (float*)ws; ws += sizeof(float)*Cq*OCq;

    k_prep<<<1, 1024, 0, stream>>>(wg1, wg2, wgcn, wout, fragbuf, woTg);
    k_conv<<<Bq*Nq, 128, 0, stream>>>(x, bg1, bg2, fragbuf, out1, xwt);
    k_graph<<<1, 1024, 0, stream>>>(ei, ew, dis, rowstart, col, val);
    k_gcn<<<8*Nq, 64, 0, stream>>>((const uint4*)xwt, rowstart, col, val, dis,
                                   bgcn, woTg, bout, y);
}